// Round 1
// baseline (465.536 us; speedup 1.0000x reference)
//
#include <hip/hip_runtime.h>

#define NDIM 512
#define NN (512*512)

// ---------------- GEMM: 64x64 tile, BK=32, 256 threads, 4x4 per thread ----------------
// stage 0: z=b*5+w.  w==0: AA[b]  = A[b]@A[b]        w>0: MIX[i,b]  = s_in[i,b]@A[b]
// stage 1: z=b*5+w.  w==0: AAA[b] = A[b]@AA[b]       w>0: MIX[i,b] += A[b]@s_in[i,b]
__global__ __launch_bounds__(256) void gemm_stage_kernel(
    const float* __restrict__ s_in, const float* __restrict__ a_o,
    float* __restrict__ AA, float* __restrict__ AAA, float* __restrict__ MIX,
    int stage)
{
    const int z = blockIdx.z;
    const int b = z / 5;
    const int w = z - b * 5;
    const float* A = a_o + b * NN;
    const float* X;
    const float* Y;
    float* C;
    bool acc = false;
    if (stage == 0) {
        Y = A;
        if (w == 0) { X = A; C = AA + b * NN; }
        else        { X = s_in + ((w - 1) * 8 + b) * NN; C = MIX + ((w - 1) * 8 + b) * NN; }
    } else {
        X = A;
        if (w == 0) { Y = AA + b * NN; C = AAA + b * NN; }
        else        { Y = s_in + ((w - 1) * 8 + b) * NN; C = MIX + ((w - 1) * 8 + b) * NN; acc = true; }
    }

    __shared__ float As[64][33];   // padded: scalar column reads conflict-free
    __shared__ float Bs[32][64];   // float4 row reads

    const int tid = threadIdx.x;
    const int tx = tid & 15, ty = tid >> 4;
    const int row0 = blockIdx.y * 64, col0 = blockIdx.x * 64;

    float accum[4][4];
    #pragma unroll
    for (int u = 0; u < 4; ++u)
        #pragma unroll
        for (int v = 0; v < 4; ++v) accum[u][v] = 0.f;

    for (int k0 = 0; k0 < NDIM; k0 += 32) {
        // As: 64 rows x 32 k-cols (row-major from X)
        #pragma unroll
        for (int f = tid; f < 512; f += 256) {
            const int r = f >> 3, c4 = (f & 7) << 2;
            float4 v = *(const float4*)(X + (row0 + r) * NDIM + k0 + c4);
            As[r][c4 + 0] = v.x; As[r][c4 + 1] = v.y;
            As[r][c4 + 2] = v.z; As[r][c4 + 3] = v.w;
        }
        // Bs: 32 k-rows x 64 cols
        #pragma unroll
        for (int f = tid; f < 512; f += 256) {
            const int r = f >> 4, c4 = (f & 15) << 2;
            *(float4*)&Bs[r][c4] = *(const float4*)(Y + (k0 + r) * NDIM + col0 + c4);
        }
        __syncthreads();
        #pragma unroll
        for (int k = 0; k < 32; ++k) {
            float av[4];
            #pragma unroll
            for (int u = 0; u < 4; ++u) av[u] = As[ty * 4 + u][k];
            const float4 bv = *(const float4*)&Bs[k][tx * 4];
            const float bvv[4] = { bv.x, bv.y, bv.z, bv.w };
            #pragma unroll
            for (int u = 0; u < 4; ++u)
                #pragma unroll
                for (int v = 0; v < 4; ++v)
                    accum[u][v] = fmaf(av[u], bvv[v], accum[u][v]);
        }
        __syncthreads();
    }

    #pragma unroll
    for (int u = 0; u < 4; ++u) {
        float* crow = C + (row0 + ty * 4 + u) * NDIM + col0 + tx * 4;
        float4 v = make_float4(accum[u][0], accum[u][1], accum[u][2], accum[u][3]);
        if (acc) {
            const float4 old = *(const float4*)crow;
            v.x += old.x; v.y += old.y; v.z += old.z; v.w += old.w;
        }
        *(float4*)crow = v;
    }
}

// ---------------- Combine: temp[o,b,n,m] + per-(o,b) max-abs ----------------
__global__ __launch_bounds__(256) void combine_kernel(
    const float* __restrict__ s_in, const float* __restrict__ a_o,
    const float* __restrict__ AA, const float* __restrict__ AAA,
    const float* __restrict__ MIX,
    const float* __restrict__ alpha, const float* __restrict__ beta,
    const float* __restrict__ coeffs,
    float* __restrict__ out, unsigned int* __restrict__ smax)
{
    const int b  = blockIdx.y;
    const int e0 = blockIdx.x * 1024 + threadIdx.x * 4;   // 4 elems/thread
    const int n  = e0 >> 9;
    const int m0 = e0 & 511;

    // effective poly coeffs: off-diag poly = (c1-3c3)*A + 2c2*AA + 4c3*AAA
    float ca[8], cb[8], cc[8];
    #pragma unroll
    for (int o = 0; o < 8; ++o) {
        float c1 = 0.f, c2 = 0.f, c3 = 0.f;
        #pragma unroll
        for (int i = 0; i < 4; ++i) {
            c1 += coeffs[o * 16 + 4 + i];
            c2 += coeffs[o * 16 + 8 + i];
            c3 += coeffs[o * 16 + 12 + i];
        }
        ca[o] = c1 - 3.f * c3; cb[o] = 2.f * c2; cc[o] = 4.f * c3;
    }

    float av[4], aav[4], aaav[4], sv[4][4], mv[4][4];
    {
        const float4 a4   = *(const float4*)(a_o + b * NN + e0);
        const float4 aa4  = *(const float4*)(AA  + b * NN + e0);
        const float4 aaa4 = *(const float4*)(AAA + b * NN + e0);
        av[0]=a4.x; av[1]=a4.y; av[2]=a4.z; av[3]=a4.w;
        aav[0]=aa4.x; aav[1]=aa4.y; aav[2]=aa4.z; aav[3]=aa4.w;
        aaav[0]=aaa4.x; aaav[1]=aaa4.y; aaav[2]=aaa4.z; aaav[3]=aaa4.w;
        #pragma unroll
        for (int i = 0; i < 4; ++i) {
            const float4 s4 = *(const float4*)(s_in + (i * 8 + b) * NN + e0);
            const float4 m4 = *(const float4*)(MIX  + (i * 8 + b) * NN + e0);
            sv[i][0]=s4.x; sv[i][1]=s4.y; sv[i][2]=s4.z; sv[i][3]=s4.w;
            mv[i][0]=m4.x; mv[i][1]=m4.y; mv[i][2]=m4.z; mv[i][3]=m4.w;
        }
    }

    float lmax[8];
    #pragma unroll
    for (int o = 0; o < 8; ++o) {
        float outv[4];
        float lm = 0.f;
        #pragma unroll
        for (int j = 0; j < 4; ++j) {
            float t = ca[o] * av[j] + cb[o] * aav[j] + cc[o] * aaav[j];
            #pragma unroll
            for (int i = 0; i < 4; ++i)
                t += alpha[o * 4 + i] * sv[i][j] + beta[o * 4 + i] * mv[i][j];
            t *= 0.25f;
            if (n == m0 + j) t = 0.f;
            outv[j] = t;
            lm = fmaxf(lm, fabsf(t));
        }
        lmax[o] = lm;
        *(float4*)(out + (o * 8 + b) * NN + e0) =
            make_float4(outv[0], outv[1], outv[2], outv[3]);
    }

    // wave reduce (64 lanes) then cross-wave via LDS, one atomic per (block,o)
    #pragma unroll
    for (int o = 0; o < 8; ++o) {
        #pragma unroll
        for (int off = 32; off > 0; off >>= 1)
            lmax[o] = fmaxf(lmax[o], __shfl_xor(lmax[o], off, 64));
    }
    __shared__ float red[4][8];
    const int lane = threadIdx.x & 63, wv = threadIdx.x >> 6;
    if (lane == 0) {
        #pragma unroll
        for (int o = 0; o < 8; ++o) red[wv][o] = lmax[o];
    }
    __syncthreads();
    if (threadIdx.x < 8) {
        const int o = threadIdx.x;
        const float mfin = fmaxf(fmaxf(red[0][o], red[1][o]), fmaxf(red[2][o], red[3][o]));
        atomicMax(&smax[o * 8 + b], __float_as_uint(mfin));
    }
}

// ---------------- Normalize + relu, in place on d_out ----------------
__global__ __launch_bounds__(256) void norm_kernel(
    float* __restrict__ out, const unsigned int* __restrict__ smax,
    const float* __restrict__ tau)
{
    const int ob = blockIdx.y;
    const float mx = __uint_as_float(smax[ob]);
    const float inv = (mx == 0.f) ? 1.f : (1.f / mx);
    const float t = tau[ob >> 3];
    const int e0 = blockIdx.x * 1024 + threadIdx.x * 4;
    float4 v = *(float4*)(out + ob * NN + e0);
    v.x = fmaxf(fmaf(v.x, inv, -t), 0.f);
    v.y = fmaxf(fmaf(v.y, inv, -t), 0.f);
    v.z = fmaxf(fmaf(v.z, inv, -t), 0.f);
    v.w = fmaxf(fmaf(v.w, inv, -t), 0.f);
    *(float4*)(out + ob * NN + e0) = v;
}

extern "C" void kernel_launch(void* const* d_in, const int* in_sizes, int n_in,
                              void* d_out, int out_size, void* d_ws, size_t ws_size,
                              hipStream_t stream) {
    const float* s_in   = (const float*)d_in[0];  // (4,8,512,512)
    const float* a_o    = (const float*)d_in[1];  // (8,512,512)
    const float* alpha  = (const float*)d_in[2];  // (8,4)
    const float* beta   = (const float*)d_in[3];  // (8,4)
    const float* coeffs = (const float*)d_in[4];  // (8,4,4)
    const float* tau    = (const float*)d_in[5];  // (8)
    float* out = (float*)d_out;                   // (8,8,512,512)

    float* AA  = (float*)d_ws;                    // 8*NN
    float* AAA = AA + 8 * NN;                     // 8*NN
    float* MIX = AAA + 8 * NN;                    // 32*NN
    unsigned int* SMAX = (unsigned int*)(MIX + 32 * NN);  // 64

    const dim3 gblock(256);
    const dim3 ggrid(8, 8, 40);
    hipLaunchKernelGGL(gemm_stage_kernel, ggrid, gblock, 0, stream,
                       s_in, a_o, AA, AAA, MIX, 0);
    hipLaunchKernelGGL(gemm_stage_kernel, ggrid, gblock, 0, stream,
                       s_in, a_o, AA, AAA, MIX, 1);
    hipMemsetAsync(SMAX, 0, 64 * sizeof(unsigned int), stream);
    hipLaunchKernelGGL(combine_kernel, dim3(256, 8), dim3(256), 0, stream,
                       s_in, a_o, AA, AAA, MIX, alpha, beta, coeffs, out, SMAX);
    hipLaunchKernelGGL(norm_kernel, dim3(256, 64), dim3(256), 0, stream,
                       out, SMAX, tau);
}

// Round 5
// 266.006 us; speedup vs baseline: 1.7501x; 1.7501x over previous
//
#include <hip/hip_runtime.h>

#define NDIM 512
#define NN (512*512)

typedef float          fv4  __attribute__((ext_vector_type(4)));
typedef unsigned int   uv2  __attribute__((ext_vector_type(2)));
typedef unsigned int   uv4  __attribute__((ext_vector_type(4)));
typedef unsigned short usv4 __attribute__((ext_vector_type(4)));
typedef short          sv8  __attribute__((ext_vector_type(8)));

__device__ __forceinline__ unsigned short f2bf(float x){
    unsigned u = __builtin_bit_cast(unsigned, x);
    u += 0x7fffu + ((u >> 16) & 1u);          // round-to-nearest-even
    return (unsigned short)(u >> 16);
}
__device__ __forceinline__ float bf2f(unsigned short s){
    unsigned u = ((unsigned)s) << 16;
    return __builtin_bit_cast(float, u);
}

// D += A*B, bf16 16x16x32 (builtin; short8 = 8 bf16 per operand)
#define MFMA16(acc, va, vb) \
    acc = __builtin_amdgcn_mfma_f32_16x16x32_bf16( \
        __builtin_bit_cast(sv8, va), __builtin_bit_cast(sv8, vb), acc, 0, 0, 0)

// hardware transpose read: 16-lane cluster reads its contiguous 128B subtile
// (addr(l) = base + 8*l B); lane l receives elems (l&15) + j*16 + (l>>4)*64
#define TRREAD(dst, addr) \
    asm volatile("ds_read_b64_tr_b16 %0, %1" : "=v"(dst) : "v"(addr))

// ---- staging helpers -------------------------------------------------------
// X-tile (left operand rows): row-major [128][36] (pad 4 -> 72B rows, 8B aligned)
template<bool DO_LO>
__device__ __forceinline__ void stage_x(const float* __restrict__ X, int row0, int k0, int tid,
                                        unsigned short (*__restrict__ H)[36],
                                        unsigned short (*__restrict__ L)[36]){
    #pragma unroll
    for (int it = 0; it < 4; ++it) {
        int f  = tid + it * 256;
        int r  = f >> 3, c4 = (f & 7) << 2;
        float4 v = *(const float4*)(X + (row0 + r) * NDIM + k0 + c4);
        float vv[4] = {v.x, v.y, v.z, v.w};
        usv4 h, l;
        #pragma unroll
        for (int j = 0; j < 4; ++j) {
            unsigned short hb = f2bf(vv[j]);
            h[j] = hb;
            l[j] = f2bf(vv[j] - bf2f(hb));
        }
        *(usv4*)&H[r][c4] = h;
        if (DO_LO) *(usv4*)&L[r][c4] = l;
    }
}
// B-tile (right operand, row-major source): subtiled [cs(8)][k(32)][c(16)]
template<bool DO_LO>
__device__ __forceinline__ void stage_b(const float* __restrict__ Y, int col0, int k0, int tid,
                                        unsigned short* __restrict__ H,
                                        unsigned short* __restrict__ L){
    #pragma unroll
    for (int it = 0; it < 4; ++it) {
        int f   = tid + it * 256;
        int rg  = f >> 6;                 // 16 regions of 8k x 32c
        int k   = (rg & 3) * 8 + ((f & 63) >> 3);
        int c4  = (rg >> 2) * 32 + (f & 7) * 4;
        float4 v = *(const float4*)(Y + (k0 + k) * NDIM + col0 + c4);
        float vv[4] = {v.x, v.y, v.z, v.w};
        usv4 h, l;
        #pragma unroll
        for (int j = 0; j < 4; ++j) {
            unsigned short hb = f2bf(vv[j]);
            h[j] = hb;
            l[j] = f2bf(vv[j] - bf2f(hb));
        }
        int idx = (c4 >> 4) * 512 + k * 16 + (c4 & 15);
        *(usv4*)&H[idx] = h;
        if (DO_LO) *(usv4*)&L[idx] = l;
    }
}

// ---- split GEMM (fp32-accurate via hi/lo bf16): C = X @ Y ------------------
// used for AA = A@A and AAA = A@AA. grid (4,4,8), block 256.
__global__ __launch_bounds__(256) void gemm_split_kernel(
    const float* __restrict__ Xbase, const float* __restrict__ Ybase,
    float* __restrict__ Cbase)
{
    const int b = blockIdx.z;
    const float* X = Xbase + b * NN;
    const float* Y = Ybase + b * NN;
    float* C = Cbase + b * NN;
    const int row0 = blockIdx.y * 128, col0 = blockIdx.x * 128;
    const int tid = threadIdx.x, lane = tid & 63, w = tid >> 6;

    __shared__ unsigned short Xh[128][36], Xl[128][36];
    __shared__ unsigned short Bh[4096], Bl[4096];

    fv4 acc[4][4];
    #pragma unroll
    for (int mi = 0; mi < 4; ++mi)
        #pragma unroll
        for (int ni = 0; ni < 4; ++ni) acc[mi][ni] = (fv4)0.f;

    const unsigned bh_base = (unsigned)(uintptr_t)&Bh[0];
    const unsigned bl_base = (unsigned)(uintptr_t)&Bl[0];
    const unsigned laneoff = (((unsigned)lane >> 4) << 7) | (((unsigned)lane & 15) << 3);
    const unsigned wcol    = ((unsigned)(w & 1)) << 12;   // (w&1)*4 cs-blocks * 1024B

    for (int k0 = 0; k0 < NDIM; k0 += 32) {
        stage_x<true>(X, row0, k0, tid, Xh, Xl);
        stage_b<true>(Y, col0, k0, tid, Bh, Bl);
        __syncthreads();

        uv2 bhf[4][2], blf[4][2];
        #pragma unroll
        for (int ni = 0; ni < 4; ++ni)
            #pragma unroll
            for (int h = 0; h < 2; ++h) {
                TRREAD(bhf[ni][h], bh_base + wcol + laneoff + ni * 1024 + h * 512);
                TRREAD(blf[ni][h], bl_base + wcol + laneoff + ni * 1024 + h * 512);
            }
        asm volatile("s_waitcnt lgkmcnt(0)" ::: "memory");
        __builtin_amdgcn_sched_barrier(0);

        const int g4 = (lane >> 4) * 4;
        #pragma unroll
        for (int mi = 0; mi < 4; ++mi) {
            const unsigned short* xrh = &Xh[(w >> 1) * 64 + mi * 16 + (lane & 15)][0];
            const unsigned short* xrl = &Xl[(w >> 1) * 64 + mi * 16 + (lane & 15)][0];
            uv2 h0 = *(const uv2*)(xrh + g4);
            uv2 h1 = *(const uv2*)(xrh + 16 + g4);
            uv2 l0 = *(const uv2*)(xrl + g4);
            uv2 l1 = *(const uv2*)(xrl + 16 + g4);
            uv4 ah = {h0.x, h0.y, h1.x, h1.y};
            uv4 al = {l0.x, l0.y, l1.x, l1.y};
            #pragma unroll
            for (int ni = 0; ni < 4; ++ni) {
                uv4 vbh = {bhf[ni][0].x, bhf[ni][0].y, bhf[ni][1].x, bhf[ni][1].y};
                uv4 vbl = {blf[ni][0].x, blf[ni][0].y, blf[ni][1].x, blf[ni][1].y};
                MFMA16(acc[mi][ni], ah, vbh);
                MFMA16(acc[mi][ni], ah, vbl);
                MFMA16(acc[mi][ni], al, vbh);
            }
        }
        __syncthreads();
    }

    const int g = lane >> 4, c15 = lane & 15;
    #pragma unroll
    for (int mi = 0; mi < 4; ++mi)
        #pragma unroll
        for (int ni = 0; ni < 4; ++ni) {
            int r = row0 + (w >> 1) * 64 + mi * 16 + g * 4;
            int c = col0 + (w & 1) * 64 + ni * 16 + c15;
            #pragma unroll
            for (int q = 0; q < 4; ++q)
                C[(r + q) * NDIM + c] = acc[mi][ni][q];
        }
}

// ---- MIX GEMM (plain bf16): C = S @ A + A @ S ------------------------------
// grid (4,4,32) z = i*8+b, block 256.
__global__ __launch_bounds__(256) void gemm_mix_kernel(
    const float* __restrict__ s_in, const float* __restrict__ a_o,
    float* __restrict__ MIX)
{
    const int z = blockIdx.z;
    const int b = z & 7;
    const float* S = s_in + z * NN;
    const float* A = a_o + b * NN;
    float* C = MIX + z * NN;
    const int row0 = blockIdx.y * 128, col0 = blockIdx.x * 128;
    const int tid = threadIdx.x, lane = tid & 63, w = tid >> 6;

    __shared__ unsigned short Xs1[128][36], Xs2[128][36];
    __shared__ unsigned short B1[4096], B2[4096];

    fv4 acc[4][4];
    #pragma unroll
    for (int mi = 0; mi < 4; ++mi)
        #pragma unroll
        for (int ni = 0; ni < 4; ++ni) acc[mi][ni] = (fv4)0.f;

    const unsigned b1_base = (unsigned)(uintptr_t)&B1[0];
    const unsigned b2_base = (unsigned)(uintptr_t)&B2[0];
    const unsigned laneoff = (((unsigned)lane >> 4) << 7) | (((unsigned)lane & 15) << 3);
    const unsigned wcol    = ((unsigned)(w & 1)) << 12;

    for (int k0 = 0; k0 < NDIM; k0 += 32) {
        stage_x<false>(S, row0, k0, tid, Xs1, nullptr);  // S rows   (S@A)
        stage_b<false>(A, col0, k0, tid, B1, nullptr);   // A cols   (S@A)
        stage_x<false>(A, row0, k0, tid, Xs2, nullptr);  // A rows   (A@S)
        stage_b<false>(S, col0, k0, tid, B2, nullptr);   // S cols   (A@S)
        __syncthreads();

        uv2 f1[4][2], f2[4][2];
        #pragma unroll
        for (int ni = 0; ni < 4; ++ni)
            #pragma unroll
            for (int h = 0; h < 2; ++h) {
                TRREAD(f1[ni][h], b1_base + wcol + laneoff + ni * 1024 + h * 512);
                TRREAD(f2[ni][h], b2_base + wcol + laneoff + ni * 1024 + h * 512);
            }
        asm volatile("s_waitcnt lgkmcnt(0)" ::: "memory");
        __builtin_amdgcn_sched_barrier(0);

        const int g4 = (lane >> 4) * 4;
        #pragma unroll
        for (int mi = 0; mi < 4; ++mi) {
            const unsigned short* x1 = &Xs1[(w >> 1) * 64 + mi * 16 + (lane & 15)][0];
            const unsigned short* x2 = &Xs2[(w >> 1) * 64 + mi * 16 + (lane & 15)][0];
            uv2 a10 = *(const uv2*)(x1 + g4);
            uv2 a11 = *(const uv2*)(x1 + 16 + g4);
            uv2 a20 = *(const uv2*)(x2 + g4);
            uv2 a21 = *(const uv2*)(x2 + 16 + g4);
            uv4 va1 = {a10.x, a10.y, a11.x, a11.y};
            uv4 va2 = {a20.x, a20.y, a21.x, a21.y};
            #pragma unroll
            for (int ni = 0; ni < 4; ++ni) {
                uv4 vb1 = {f1[ni][0].x, f1[ni][0].y, f1[ni][1].x, f1[ni][1].y};
                uv4 vb2 = {f2[ni][0].x, f2[ni][0].y, f2[ni][1].x, f2[ni][1].y};
                MFMA16(acc[mi][ni], va1, vb1);
                MFMA16(acc[mi][ni], va2, vb2);
            }
        }
        __syncthreads();
    }

    const int g = lane >> 4, c15 = lane & 15;
    #pragma unroll
    for (int mi = 0; mi < 4; ++mi)
        #pragma unroll
        for (int ni = 0; ni < 4; ++ni) {
            int r = row0 + (w >> 1) * 64 + mi * 16 + g * 4;
            int c = col0 + (w & 1) * 64 + ni * 16 + c15;
            #pragma unroll
            for (int q = 0; q < 4; ++q)
                C[(r + q) * NDIM + c] = acc[mi][ni][q];
        }
}

// ---------------- Combine: temp[o,b,n,m] + per-(o,b) max-abs ----------------
__global__ __launch_bounds__(256) void combine_kernel(
    const float* __restrict__ s_in, const float* __restrict__ a_o,
    const float* __restrict__ AA, const float* __restrict__ AAA,
    const float* __restrict__ MIX,
    const float* __restrict__ alpha, const float* __restrict__ beta,
    const float* __restrict__ coeffs,
    float* __restrict__ out, unsigned int* __restrict__ smax)
{
    const int b  = blockIdx.y;
    const int e0 = blockIdx.x * 1024 + threadIdx.x * 4;
    const int n  = e0 >> 9;
    const int m0 = e0 & 511;

    float ca[8], cb[8], cc[8];
    #pragma unroll
    for (int o = 0; o < 8; ++o) {
        float c1 = 0.f, c2 = 0.f, c3 = 0.f;
        #pragma unroll
        for (int i = 0; i < 4; ++i) {
            c1 += coeffs[o * 16 + 4 + i];
            c2 += coeffs[o * 16 + 8 + i];
            c3 += coeffs[o * 16 + 12 + i];
        }
        ca[o] = c1 - 3.f * c3; cb[o] = 2.f * c2; cc[o] = 4.f * c3;
    }

    float av[4], aav[4], aaav[4], sv[4][4], mv[4][4];
    {
        const float4 a4   = *(const float4*)(a_o + b * NN + e0);
        const float4 aa4  = *(const float4*)(AA  + b * NN + e0);
        const float4 aaa4 = *(const float4*)(AAA + b * NN + e0);
        av[0]=a4.x; av[1]=a4.y; av[2]=a4.z; av[3]=a4.w;
        aav[0]=aa4.x; aav[1]=aa4.y; aav[2]=aa4.z; aav[3]=aa4.w;
        aaav[0]=aaa4.x; aaav[1]=aaa4.y; aaav[2]=aaa4.z; aaav[3]=aaa4.w;
        #pragma unroll
        for (int i = 0; i < 4; ++i) {
            const float4 s4 = *(const float4*)(s_in + (i * 8 + b) * NN + e0);
            const float4 m4 = *(const float4*)(MIX  + (i * 8 + b) * NN + e0);
            sv[i][0]=s4.x; sv[i][1]=s4.y; sv[i][2]=s4.z; sv[i][3]=s4.w;
            mv[i][0]=m4.x; mv[i][1]=m4.y; mv[i][2]=m4.z; mv[i][3]=m4.w;
        }
    }

    float lmax[8];
    #pragma unroll
    for (int o = 0; o < 8; ++o) {
        float outv[4];
        float lm = 0.f;
        #pragma unroll
        for (int j = 0; j < 4; ++j) {
            float t = ca[o] * av[j] + cb[o] * aav[j] + cc[o] * aaav[j];
            #pragma unroll
            for (int i = 0; i < 4; ++i)
                t += alpha[o * 4 + i] * sv[i][j] + beta[o * 4 + i] * mv[i][j];
            t *= 0.25f;
            if (n == m0 + j) t = 0.f;
            outv[j] = t;
            lm = fmaxf(lm, fabsf(t));
        }
        lmax[o] = lm;
        *(float4*)(out + (o * 8 + b) * NN + e0) =
            make_float4(outv[0], outv[1], outv[2], outv[3]);
    }

    #pragma unroll
    for (int o = 0; o < 8; ++o) {
        #pragma unroll
        for (int off = 32; off > 0; off >>= 1)
            lmax[o] = fmaxf(lmax[o], __shfl_xor(lmax[o], off, 64));
    }
    __shared__ float red[4][8];
    const int lane = threadIdx.x & 63, wv = threadIdx.x >> 6;
    if (lane == 0) {
        #pragma unroll
        for (int o = 0; o < 8; ++o) red[wv][o] = lmax[o];
    }
    __syncthreads();
    if (threadIdx.x < 8) {
        const int o = threadIdx.x;
        const float mfin = fmaxf(fmaxf(red[0][o], red[1][o]), fmaxf(red[2][o], red[3][o]));
        atomicMax(&smax[o * 8 + b], __float_as_uint(mfin));
    }
}

// ---------------- Normalize + relu, in place on d_out ----------------
__global__ __launch_bounds__(256) void norm_kernel(
    float* __restrict__ out, const unsigned int* __restrict__ smax,
    const float* __restrict__ tau)
{
    const int ob = blockIdx.y;
    const float mx = __uint_as_float(smax[ob]);
    const float inv = (mx == 0.f) ? 1.f : (1.f / mx);
    const float t = tau[ob >> 3];
    const int e0 = blockIdx.x * 1024 + threadIdx.x * 4;
    float4 v = *(float4*)(out + ob * NN + e0);
    v.x = fmaxf(fmaf(v.x, inv, -t), 0.f);
    v.y = fmaxf(fmaf(v.y, inv, -t), 0.f);
    v.z = fmaxf(fmaf(v.z, inv, -t), 0.f);
    v.w = fmaxf(fmaf(v.w, inv, -t), 0.f);
    *(float4*)(out + ob * NN + e0) = v;
}

extern "C" void kernel_launch(void* const* d_in, const int* in_sizes, int n_in,
                              void* d_out, int out_size, void* d_ws, size_t ws_size,
                              hipStream_t stream) {
    (void)in_sizes; (void)n_in; (void)out_size; (void)ws_size;
    const float* s_in   = (const float*)d_in[0];  // (4,8,512,512)
    const float* a_o    = (const float*)d_in[1];  // (8,512,512)
    const float* alpha  = (const float*)d_in[2];  // (8,4)
    const float* beta   = (const float*)d_in[3];  // (8,4)
    const float* coeffs = (const float*)d_in[4];  // (8,4,4)
    const float* tau    = (const float*)d_in[5];  // (8)
    float* out = (float*)d_out;                   // (8,8,512,512)

    float* AA  = (float*)d_ws;                    // 8*NN fp32
    float* AAA = AA + 8 * NN;                     // 8*NN fp32
    float* MIX = AAA + 8 * NN;                    // 32*NN fp32
    unsigned int* SMAX = (unsigned int*)(MIX + 32 * NN);  // 64

    hipLaunchKernelGGL(gemm_split_kernel, dim3(4, 4, 8), dim3(256), 0, stream,
                       a_o, a_o, AA);                       // AA = A@A
    hipLaunchKernelGGL(gemm_split_kernel, dim3(4, 4, 8), dim3(256), 0, stream,
                       a_o, AA, AAA);                       // AAA = A@AA
    hipLaunchKernelGGL(gemm_mix_kernel, dim3(4, 4, 32), dim3(256), 0, stream,
                       s_in, a_o, MIX);                     // MIX = S@A + A@S
    hipMemsetAsync(SMAX, 0, 64 * sizeof(unsigned int), stream);
    hipLaunchKernelGGL(combine_kernel, dim3(256, 8), dim3(256), 0, stream,
                       s_in, a_o, AA, AAA, MIX, alpha, beta, coeffs, out, SMAX);
    hipLaunchKernelGGL(norm_kernel, dim3(256, 64), dim3(256), 0, stream,
                       out, SMAX, tau);
}

// Round 6
// 254.317 us; speedup vs baseline: 1.8305x; 1.0460x over previous
//
#include <hip/hip_runtime.h>

#define NDIM 512
#define NN (512*512)

typedef float          fv4  __attribute__((ext_vector_type(4)));
typedef unsigned int   uv2  __attribute__((ext_vector_type(2)));
typedef unsigned int   uv4  __attribute__((ext_vector_type(4)));
typedef unsigned short usv4 __attribute__((ext_vector_type(4)));
typedef unsigned short usv8 __attribute__((ext_vector_type(8)));
typedef short          sv8  __attribute__((ext_vector_type(8)));

__device__ __forceinline__ unsigned short f2bf(float x){
    unsigned u = __builtin_bit_cast(unsigned, x);
    u += 0x7fffu + ((u >> 16) & 1u);          // round-to-nearest-even
    return (unsigned short)(u >> 16);
}
__device__ __forceinline__ float bf2f(unsigned short s){
    unsigned u = ((unsigned)s) << 16;
    return __builtin_bit_cast(float, u);
}

// D += A*B, bf16 16x16x32 (builtin; short8 = 8 bf16 per operand)
#define MFMA16(acc, va, vb) \
    acc = __builtin_amdgcn_mfma_f32_16x16x32_bf16( \
        __builtin_bit_cast(sv8, va), __builtin_bit_cast(sv8, vb), acc, 0, 0, 0)

// hardware transpose read: 16-lane cluster reads its contiguous 128B subtile
// (addr(l) = base + 8*l B); lane l receives elems (l&15) + j*16 + (l>>4)*64
#define TRREAD(dst, addr) \
    asm volatile("ds_read_b64_tr_b16 %0, %1" : "=v"(dst) : "v"(addr))

// ---------------- pre-convert: s_in -> bf16, a_o -> hi/lo bf16 --------------
__global__ __launch_bounds__(256) void preconv_kernel(
    const float* __restrict__ s_in, const float* __restrict__ a_o,
    unsigned short* __restrict__ s_bf, unsigned short* __restrict__ Ah,
    unsigned short* __restrict__ Al)
{
    const int z  = blockIdx.y;
    const int e0 = blockIdx.x * 1024 + threadIdx.x * 4;
    if (z < 32) {
        float4 v = *(const float4*)(s_in + z * NN + e0);
        float vv[4] = {v.x, v.y, v.z, v.w};
        usv4 o;
        #pragma unroll
        for (int j = 0; j < 4; ++j) o[j] = f2bf(vv[j]);
        *(usv4*)(s_bf + z * NN + e0) = o;
    } else {
        const int b = z - 32;
        float4 v = *(const float4*)(a_o + b * NN + e0);
        float vv[4] = {v.x, v.y, v.z, v.w};
        usv4 h, l;
        #pragma unroll
        for (int j = 0; j < 4; ++j) {
            unsigned short hb = f2bf(vv[j]);
            h[j] = hb;
            l[j] = f2bf(vv[j] - bf2f(hb));
        }
        *(usv4*)(Ah + b * NN + e0) = h;
        *(usv4*)(Al + b * NN + e0) = l;
    }
}

// ---- bf16 staging helpers --------------------------------------------------
// X-tile rows: [128][40] (80B rows, 16B aligned stores)
__device__ __forceinline__ void stage_x8(const unsigned short* __restrict__ X,
                                         int row0, int k0, int tid,
                                         unsigned short (*__restrict__ H)[40]){
    #pragma unroll
    for (int it = 0; it < 2; ++it) {
        int f = tid + it * 256;               // 0..511
        int r = f >> 2, c8 = (f & 3) << 3;
        *(usv8*)&H[r][c8] = *(const usv8*)(X + (row0 + r) * NDIM + k0 + c8);
    }
}
// B-tile (row-major source) -> subtiled [cs(8)][k(32)][c(16)]
__device__ __forceinline__ void stage_b8(const unsigned short* __restrict__ Y,
                                         int col0, int k0, int tid,
                                         unsigned short* __restrict__ Bs){
    #pragma unroll
    for (int it = 0; it < 2; ++it) {
        int f  = tid + it * 256;              // 0..511
        int k  = f >> 4, rem = f & 15;
        int cs = rem >> 1, h = rem & 1;
        *(usv8*)&Bs[cs * 512 + k * 16 + h * 8] =
            *(const usv8*)(Y + (k0 + k) * NDIM + col0 + cs * 16 + h * 8);
    }
}

// ---- unified GEMM kernel ---------------------------------------------------
// stage==0: grid (4,4,8)  all blocks SPLIT: AA = A@A (fp32 + hi/lo bf16 out)
// stage==1: grid (4,4,40) z<8 SPLIT: AAA = A@AA (fp32)
//                         z>=8 MIX : MIXbf[z-8] = bf16(S@A + A@S)
__global__ __launch_bounds__(256) void gemm_fused_kernel(
    const unsigned short* __restrict__ s_bf,
    const unsigned short* __restrict__ Ah, const unsigned short* __restrict__ Al,
    unsigned short* __restrict__ AAh, unsigned short* __restrict__ AAl,
    float* __restrict__ AA, float* __restrict__ AAA,
    unsigned short* __restrict__ MIXbf, int stage)
{
    const int z = blockIdx.z;
    const bool split = (stage == 0) || (z < 8);

    const unsigned short *X1, *X2, *Y1, *Y2;
    if (stage == 0)      { X1 = Ah + z * NN;  X2 = Al + z * NN;
                           Y1 = Ah + z * NN;  Y2 = Al + z * NN; }
    else if (z < 8)      { X1 = Ah + z * NN;  X2 = Al + z * NN;
                           Y1 = AAh + z * NN; Y2 = AAl + z * NN; }
    else                 { const int z2 = z - 8, b = z2 & 7;
                           X1 = s_bf + z2 * NN; X2 = Ah + b * NN;
                           Y1 = Ah + b * NN;    Y2 = s_bf + z2 * NN; }

    const int row0 = blockIdx.y * 128, col0 = blockIdx.x * 128;
    const int tid = threadIdx.x, lane = tid & 63, w = tid >> 6;

    __shared__ unsigned short Xa[128][40], Xb[128][40];
    __shared__ unsigned short Ba[4096], Bb[4096];

    fv4 acc[4][4];
    #pragma unroll
    for (int mi = 0; mi < 4; ++mi)
        #pragma unroll
        for (int ni = 0; ni < 4; ++ni) acc[mi][ni] = (fv4)0.f;

    const unsigned ba_base = (unsigned)(uintptr_t)&Ba[0];
    const unsigned bb_base = (unsigned)(uintptr_t)&Bb[0];
    const unsigned laneoff = (((unsigned)lane >> 4) << 7) | (((unsigned)lane & 15) << 3);
    const unsigned wcol    = ((unsigned)(w & 1)) << 12;   // (w&1)*4 cs-blocks * 1024B

    for (int k0 = 0; k0 < NDIM; k0 += 32) {
        stage_x8(X1, row0, k0, tid, Xa);
        stage_x8(X2, row0, k0, tid, Xb);
        stage_b8(Y1, col0, k0, tid, Ba);
        stage_b8(Y2, col0, k0, tid, Bb);
        __syncthreads();

        uv2 fa[4][2], fb[4][2];
        #pragma unroll
        for (int ni = 0; ni < 4; ++ni)
            #pragma unroll
            for (int h = 0; h < 2; ++h) {
                TRREAD(fa[ni][h], ba_base + wcol + laneoff + ni * 1024 + h * 512);
                TRREAD(fb[ni][h], bb_base + wcol + laneoff + ni * 1024 + h * 512);
            }
        asm volatile("s_waitcnt lgkmcnt(0)" ::: "memory");
        __builtin_amdgcn_sched_barrier(0);

        const int g4 = (lane >> 4) * 4;
        #pragma unroll
        for (int mi = 0; mi < 4; ++mi) {
            const unsigned short* xr1 = &Xa[(w >> 1) * 64 + mi * 16 + (lane & 15)][0];
            const unsigned short* xr2 = &Xb[(w >> 1) * 64 + mi * 16 + (lane & 15)][0];
            uv2 a0 = *(const uv2*)(xr1 + g4);
            uv2 a1 = *(const uv2*)(xr1 + 16 + g4);
            uv2 b0 = *(const uv2*)(xr2 + g4);
            uv2 b1 = *(const uv2*)(xr2 + 16 + g4);
            uv4 xa = {a0.x, a0.y, a1.x, a1.y};
            uv4 xb = {b0.x, b0.y, b1.x, b1.y};
            #pragma unroll
            for (int ni = 0; ni < 4; ++ni) {
                uv4 vba = {fa[ni][0].x, fa[ni][0].y, fa[ni][1].x, fa[ni][1].y};
                uv4 vbb = {fb[ni][0].x, fb[ni][0].y, fb[ni][1].x, fb[ni][1].y};
                if (split) {
                    MFMA16(acc[mi][ni], xa, vba);   // hi*hi
                    MFMA16(acc[mi][ni], xa, vbb);   // hi*lo
                    MFMA16(acc[mi][ni], xb, vba);   // lo*hi
                } else {
                    MFMA16(acc[mi][ni], xa, vba);   // S@A
                    MFMA16(acc[mi][ni], xb, vbb);   // A@S
                }
            }
        }
        __syncthreads();
    }

    const int g = lane >> 4, c15 = lane & 15;
    if (split) {
        float* C = (stage == 0) ? (AA + z * NN) : (AAA + z * NN);
        #pragma unroll
        for (int mi = 0; mi < 4; ++mi)
            #pragma unroll
            for (int ni = 0; ni < 4; ++ni) {
                int r = row0 + (w >> 1) * 64 + mi * 16 + g * 4;
                int c = col0 + (w & 1) * 64 + ni * 16 + c15;
                #pragma unroll
                for (int q = 0; q < 4; ++q) {
                    float v = acc[mi][ni][q];
                    C[(r + q) * NDIM + c] = v;
                    if (stage == 0) {
                        unsigned short hb = f2bf(v);
                        AAh[z * NN + (r + q) * NDIM + c] = hb;
                        AAl[z * NN + (r + q) * NDIM + c] = f2bf(v - bf2f(hb));
                    }
                }
            }
    } else {
        unsigned short* Cm = MIXbf + (z - 8) * NN;
        #pragma unroll
        for (int mi = 0; mi < 4; ++mi)
            #pragma unroll
            for (int ni = 0; ni < 4; ++ni) {
                int r = row0 + (w >> 1) * 64 + mi * 16 + g * 4;
                int c = col0 + (w & 1) * 64 + ni * 16 + c15;
                #pragma unroll
                for (int q = 0; q < 4; ++q)
                    Cm[(r + q) * NDIM + c] = f2bf(acc[mi][ni][q]);
            }
    }
}

// ---------------- Combine: temp[o,b,n,m] + per-(o,b) max-abs ----------------
// 8 elems/thread, grid (128, 8)
__global__ __launch_bounds__(256) void combine_kernel(
    const unsigned short* __restrict__ s_bf, const unsigned short* __restrict__ Ah,
    const float* __restrict__ AA, const float* __restrict__ AAA,
    const unsigned short* __restrict__ MIXbf,
    const float* __restrict__ alpha, const float* __restrict__ beta,
    const float* __restrict__ coeffs,
    float* __restrict__ out, unsigned int* __restrict__ smax)
{
    const int b  = blockIdx.y;
    const int e0 = blockIdx.x * 2048 + threadIdx.x * 8;
    const int n  = e0 >> 9;
    const int m0 = e0 & 511;

    float ca[8], cb[8], cc[8];
    #pragma unroll
    for (int o = 0; o < 8; ++o) {
        float c1 = 0.f, c2 = 0.f, c3 = 0.f;
        #pragma unroll
        for (int i = 0; i < 4; ++i) {
            c1 += coeffs[o * 16 + 4 + i];
            c2 += coeffs[o * 16 + 8 + i];
            c3 += coeffs[o * 16 + 12 + i];
        }
        ca[o] = c1 - 3.f * c3; cb[o] = 2.f * c2; cc[o] = 4.f * c3;
    }

    float av[8], aav[8], aaav[8], sv[4][8], mv[4][8];
    {
        usv8 a8 = *(const usv8*)(Ah + b * NN + e0);
        #pragma unroll
        for (int j = 0; j < 8; ++j) av[j] = bf2f(a8[j]);
        const float4 q0 = *(const float4*)(AA + b * NN + e0);
        const float4 q1 = *(const float4*)(AA + b * NN + e0 + 4);
        aav[0]=q0.x; aav[1]=q0.y; aav[2]=q0.z; aav[3]=q0.w;
        aav[4]=q1.x; aav[5]=q1.y; aav[6]=q1.z; aav[7]=q1.w;
        const float4 r0 = *(const float4*)(AAA + b * NN + e0);
        const float4 r1 = *(const float4*)(AAA + b * NN + e0 + 4);
        aaav[0]=r0.x; aaav[1]=r0.y; aaav[2]=r0.z; aaav[3]=r0.w;
        aaav[4]=r1.x; aaav[5]=r1.y; aaav[6]=r1.z; aaav[7]=r1.w;
        #pragma unroll
        for (int i = 0; i < 4; ++i) {
            usv8 s8 = *(const usv8*)(s_bf + (i * 8 + b) * NN + e0);
            usv8 m8 = *(const usv8*)(MIXbf + (i * 8 + b) * NN + e0);
            #pragma unroll
            for (int j = 0; j < 8; ++j) { sv[i][j] = bf2f(s8[j]); mv[i][j] = bf2f(m8[j]); }
        }
    }

    float lmax[8];
    #pragma unroll
    for (int o = 0; o < 8; ++o) {
        float outv[8];
        float lm = 0.f;
        #pragma unroll
        for (int j = 0; j < 8; ++j) {
            float t = ca[o] * av[j] + cb[o] * aav[j] + cc[o] * aaav[j];
            #pragma unroll
            for (int i = 0; i < 4; ++i)
                t += alpha[o * 4 + i] * sv[i][j] + beta[o * 4 + i] * mv[i][j];
            t *= 0.25f;
            if (n == m0 + j) t = 0.f;
            outv[j] = t;
            lm = fmaxf(lm, fabsf(t));
        }
        lmax[o] = lm;
        *(float4*)(out + (o * 8 + b) * NN + e0) =
            make_float4(outv[0], outv[1], outv[2], outv[3]);
        *(float4*)(out + (o * 8 + b) * NN + e0 + 4) =
            make_float4(outv[4], outv[5], outv[6], outv[7]);
    }

    #pragma unroll
    for (int o = 0; o < 8; ++o) {
        #pragma unroll
        for (int off = 32; off > 0; off >>= 1)
            lmax[o] = fmaxf(lmax[o], __shfl_xor(lmax[o], off, 64));
    }
    __shared__ float red[4][8];
    const int lane = threadIdx.x & 63, wv = threadIdx.x >> 6;
    if (lane == 0) {
        #pragma unroll
        for (int o = 0; o < 8; ++o) red[wv][o] = lmax[o];
    }
    __syncthreads();
    if (threadIdx.x < 8) {
        const int o = threadIdx.x;
        const float mfin = fmaxf(fmaxf(red[0][o], red[1][o]), fmaxf(red[2][o], red[3][o]));
        atomicMax(&smax[o * 8 + b], __float_as_uint(mfin));
    }
}

// ---------------- Normalize + relu, in place on d_out ----------------
// 8 elems/thread, grid (128, 64)
__global__ __launch_bounds__(256) void norm_kernel(
    float* __restrict__ out, const unsigned int* __restrict__ smax,
    const float* __restrict__ tau)
{
    const int ob = blockIdx.y;
    const float mx = __uint_as_float(smax[ob]);
    const float inv = (mx == 0.f) ? 1.f : (1.f / mx);
    const float t = tau[ob >> 3];
    const int e0 = blockIdx.x * 2048 + threadIdx.x * 8;
    float4 v0 = *(float4*)(out + ob * NN + e0);
    float4 v1 = *(float4*)(out + ob * NN + e0 + 4);
    v0.x = fmaxf(fmaf(v0.x, inv, -t), 0.f);
    v0.y = fmaxf(fmaf(v0.y, inv, -t), 0.f);
    v0.z = fmaxf(fmaf(v0.z, inv, -t), 0.f);
    v0.w = fmaxf(fmaf(v0.w, inv, -t), 0.f);
    v1.x = fmaxf(fmaf(v1.x, inv, -t), 0.f);
    v1.y = fmaxf(fmaf(v1.y, inv, -t), 0.f);
    v1.z = fmaxf(fmaf(v1.z, inv, -t), 0.f);
    v1.w = fmaxf(fmaf(v1.w, inv, -t), 0.f);
    *(float4*)(out + ob * NN + e0) = v0;
    *(float4*)(out + ob * NN + e0 + 4) = v1;
}

extern "C" void kernel_launch(void* const* d_in, const int* in_sizes, int n_in,
                              void* d_out, int out_size, void* d_ws, size_t ws_size,
                              hipStream_t stream) {
    (void)in_sizes; (void)n_in; (void)out_size; (void)ws_size;
    const float* s_in   = (const float*)d_in[0];  // (4,8,512,512)
    const float* a_o    = (const float*)d_in[1];  // (8,512,512)
    const float* alpha  = (const float*)d_in[2];  // (8,4)
    const float* beta   = (const float*)d_in[3];  // (8,4)
    const float* coeffs = (const float*)d_in[4];  // (8,4,4)
    const float* tau    = (const float*)d_in[5];  // (8)
    float* out = (float*)d_out;                   // (8,8,512,512)

    // workspace layout (67.1 MB total)
    float* AA  = (float*)d_ws;                       // 8NN f32
    float* AAA = AA + 8 * NN;                        // 8NN f32
    unsigned short* s_bf  = (unsigned short*)(AAA + 8 * NN);  // 32NN bf16
    unsigned short* Ah    = s_bf + 32 * NN;          // 8NN
    unsigned short* Al    = Ah + 8 * NN;             // 8NN
    unsigned short* AAh   = Al + 8 * NN;             // 8NN
    unsigned short* AAl   = AAh + 8 * NN;            // 8NN
    unsigned short* MIXbf = AAl + 8 * NN;            // 32NN
    unsigned int* SMAX = (unsigned int*)(MIXbf + 32 * NN);    // 64

    hipLaunchKernelGGL(preconv_kernel, dim3(256, 40), dim3(256), 0, stream,
                       s_in, a_o, s_bf, Ah, Al);
    hipLaunchKernelGGL(gemm_fused_kernel, dim3(4, 4, 8), dim3(256), 0, stream,
                       s_bf, Ah, Al, AAh, AAl, AA, AAA, MIXbf, 0);   // AA
    hipLaunchKernelGGL(gemm_fused_kernel, dim3(4, 4, 40), dim3(256), 0, stream,
                       s_bf, Ah, Al, AAh, AAl, AA, AAA, MIXbf, 1);   // AAA + MIX
    hipMemsetAsync(SMAX, 0, 64 * sizeof(unsigned int), stream);
    hipLaunchKernelGGL(combine_kernel, dim3(128, 8), dim3(256), 0, stream,
                       s_bf, Ah, AA, AAA, MIXbf, alpha, beta, coeffs, out, SMAX);
    hipLaunchKernelGGL(norm_kernel, dim3(128, 64), dim3(256), 0, stream,
                       out, SMAX, tau);
}

// Round 7
// 253.880 us; speedup vs baseline: 1.8337x; 1.0017x over previous
//
#include <hip/hip_runtime.h>

#define NDIM 512
#define NN (512*512)

typedef float          fv4  __attribute__((ext_vector_type(4)));
typedef unsigned int   uv2  __attribute__((ext_vector_type(2)));
typedef unsigned int   uv4  __attribute__((ext_vector_type(4)));
typedef unsigned short usv4 __attribute__((ext_vector_type(4)));
typedef unsigned short usv8 __attribute__((ext_vector_type(8)));
typedef short          sv8  __attribute__((ext_vector_type(8)));

__device__ __forceinline__ unsigned short f2bf(float x){
    unsigned u = __builtin_bit_cast(unsigned, x);
    u += 0x7fffu + ((u >> 16) & 1u);          // round-to-nearest-even
    return (unsigned short)(u >> 16);
}
__device__ __forceinline__ float bf2f(unsigned short s){
    unsigned u = ((unsigned)s) << 16;
    return __builtin_bit_cast(float, u);
}

// D += A*B, bf16 16x16x32 (builtin; short8 = 8 bf16 per operand)
#define MFMA16(acc, va, vb) \
    acc = __builtin_amdgcn_mfma_f32_16x16x32_bf16( \
        __builtin_bit_cast(sv8, va), __builtin_bit_cast(sv8, vb), acc, 0, 0, 0)

// hardware transpose read: 16-lane cluster reads its contiguous 128B subtile
// (addr(l) = base + 8*l B); lane l receives elems (l&15) + j*16 + (l>>4)*64
#define TRREAD(dst, addr) \
    asm volatile("ds_read_b64_tr_b16 %0, %1" : "=v"(dst) : "v"(addr))

// ---------------- pre-convert: s_in -> bf16, a_o -> hi/lo bf16 --------------
__global__ __launch_bounds__(256) void preconv_kernel(
    const float* __restrict__ s_in, const float* __restrict__ a_o,
    unsigned short* __restrict__ s_bf, unsigned short* __restrict__ Ah,
    unsigned short* __restrict__ Al)
{
    const int z  = blockIdx.y;
    const int e0 = blockIdx.x * 1024 + threadIdx.x * 4;
    if (z < 32) {
        float4 v = *(const float4*)(s_in + z * NN + e0);
        float vv[4] = {v.x, v.y, v.z, v.w};
        usv4 o;
        #pragma unroll
        for (int j = 0; j < 4; ++j) o[j] = f2bf(vv[j]);
        *(usv4*)(s_bf + z * NN + e0) = o;
    } else {
        const int b = z - 32;
        float4 v = *(const float4*)(a_o + b * NN + e0);
        float vv[4] = {v.x, v.y, v.z, v.w};
        usv4 h, l;
        #pragma unroll
        for (int j = 0; j < 4; ++j) {
            unsigned short hb = f2bf(vv[j]);
            h[j] = hb;
            l[j] = f2bf(vv[j] - bf2f(hb));
        }
        *(usv4*)(Ah + b * NN + e0) = h;
        *(usv4*)(Al + b * NN + e0) = l;
    }
}

// ---- bf16 staging helpers --------------------------------------------------
// X-tile rows: [128][40] (80B rows, 16B aligned stores); ~2-way write conflict (free)
__device__ __forceinline__ void stage_x8(const unsigned short* __restrict__ X,
                                         int row0, int k0, int tid,
                                         unsigned short (*__restrict__ H)[40]){
    #pragma unroll
    for (int it = 0; it < 2; ++it) {
        int f = tid + it * 256;               // 0..511
        int r = f >> 2, c8 = (f & 3) << 3;
        *(usv8*)&H[r][c8] = *(const usv8*)(X + (row0 + r) * NDIM + k0 + c8);
    }
}
// B-tile (row-major source) -> subtiled [cs(8)][k(32)][c(16)]
// conflict-free mapping: per 8-lane phase, slot = 2*kl + h = perm(lane&7);
// global: wave reads 4 rows x 256B contiguous (kh = f>>6 is wave-uniform).
__device__ __forceinline__ void stage_b8(const unsigned short* __restrict__ Y,
                                         int col0, int k0, int tid,
                                         unsigned short* __restrict__ Bs){
    #pragma unroll
    for (int it = 0; it < 2; ++it) {
        int f  = tid + it * 256;              // 0..511
        int kl = f & 3, h = (f >> 2) & 1, cs = (f >> 3) & 7, kh = f >> 6;
        int k  = kh * 4 + kl;
        *(usv8*)&Bs[cs * 512 + k * 16 + h * 8] =
            *(const usv8*)(Y + (k0 + k) * NDIM + col0 + cs * 16 + h * 8);
    }
}

// ---- unified GEMM kernel ---------------------------------------------------
// stage==0: grid (4,4,8)  all blocks SPLIT: AA = A@A (fp32 + hi/lo bf16 out)
// stage==1: grid (4,4,40) z<8 SPLIT: AAA = A@AA (fp32)
//                         z>=8 MIX : MIXbf[z-8] = bf16(S@A + A@S)
__global__ __launch_bounds__(256) void gemm_fused_kernel(
    const unsigned short* __restrict__ s_bf,
    const unsigned short* __restrict__ Ah, const unsigned short* __restrict__ Al,
    unsigned short* __restrict__ AAh, unsigned short* __restrict__ AAl,
    float* __restrict__ AA, float* __restrict__ AAA,
    unsigned short* __restrict__ MIXbf, int stage)
{
    const int z = blockIdx.z;
    const bool split = (stage == 0) || (z < 8);

    const unsigned short *X1, *X2, *Y1, *Y2;
    if (stage == 0)      { X1 = Ah + z * NN;  X2 = Al + z * NN;
                           Y1 = Ah + z * NN;  Y2 = Al + z * NN; }
    else if (z < 8)      { X1 = Ah + z * NN;  X2 = Al + z * NN;
                           Y1 = AAh + z * NN; Y2 = AAl + z * NN; }
    else                 { const int z2 = z - 8, b = z2 & 7;
                           X1 = s_bf + z2 * NN; X2 = Ah + b * NN;
                           Y1 = Ah + b * NN;    Y2 = s_bf + z2 * NN; }

    const int row0 = blockIdx.y * 128, col0 = blockIdx.x * 128;
    const int tid = threadIdx.x, lane = tid & 63, w = tid >> 6;

    __shared__ unsigned short Xa[128][40], Xb[128][40];
    __shared__ unsigned short Ba[4096], Bb[4096];

    fv4 acc[4][4];
    #pragma unroll
    for (int mi = 0; mi < 4; ++mi)
        #pragma unroll
        for (int ni = 0; ni < 4; ++ni) acc[mi][ni] = (fv4)0.f;

    const unsigned ba_base = (unsigned)(uintptr_t)&Ba[0];
    const unsigned bb_base = (unsigned)(uintptr_t)&Bb[0];
    const unsigned laneoff = (((unsigned)lane >> 4) << 7) | (((unsigned)lane & 15) << 3);
    const unsigned wcol    = ((unsigned)(w & 1)) << 12;   // (w&1)*4 cs-blocks * 1024B

    for (int k0 = 0; k0 < NDIM; k0 += 32) {
        stage_x8(X1, row0, k0, tid, Xa);
        stage_x8(X2, row0, k0, tid, Xb);
        stage_b8(Y1, col0, k0, tid, Ba);
        stage_b8(Y2, col0, k0, tid, Bb);
        __syncthreads();

        uv2 fa[4][2], fb[4][2];
        #pragma unroll
        for (int ni = 0; ni < 4; ++ni)
            #pragma unroll
            for (int h = 0; h < 2; ++h) {
                TRREAD(fa[ni][h], ba_base + wcol + laneoff + ni * 1024 + h * 512);
                TRREAD(fb[ni][h], bb_base + wcol + laneoff + ni * 1024 + h * 512);
            }
        asm volatile("s_waitcnt lgkmcnt(0)" ::: "memory");
        __builtin_amdgcn_sched_barrier(0);

        const int g4 = (lane >> 4) * 4;
        #pragma unroll
        for (int mi = 0; mi < 4; ++mi) {
            const unsigned short* xr1 = &Xa[(w >> 1) * 64 + mi * 16 + (lane & 15)][0];
            const unsigned short* xr2 = &Xb[(w >> 1) * 64 + mi * 16 + (lane & 15)][0];
            uv2 a0 = *(const uv2*)(xr1 + g4);
            uv2 a1 = *(const uv2*)(xr1 + 16 + g4);
            uv2 b0 = *(const uv2*)(xr2 + g4);
            uv2 b1 = *(const uv2*)(xr2 + 16 + g4);
            uv4 xa = {a0.x, a0.y, a1.x, a1.y};
            uv4 xb = {b0.x, b0.y, b1.x, b1.y};
            #pragma unroll
            for (int ni = 0; ni < 4; ++ni) {
                uv4 vba = {fa[ni][0].x, fa[ni][0].y, fa[ni][1].x, fa[ni][1].y};
                uv4 vbb = {fb[ni][0].x, fb[ni][0].y, fb[ni][1].x, fb[ni][1].y};
                if (split) {
                    MFMA16(acc[mi][ni], xa, vba);   // hi*hi
                    MFMA16(acc[mi][ni], xa, vbb);   // hi*lo
                    MFMA16(acc[mi][ni], xb, vba);   // lo*hi
                } else {
                    MFMA16(acc[mi][ni], xa, vba);   // S@A
                    MFMA16(acc[mi][ni], xb, vbb);   // A@S
                }
            }
        }
        __syncthreads();
    }

    const int g = lane >> 4, c15 = lane & 15;
    if (split) {
        float* C = (stage == 0) ? (AA + z * NN) : (AAA + z * NN);
        #pragma unroll
        for (int mi = 0; mi < 4; ++mi)
            #pragma unroll
            for (int ni = 0; ni < 4; ++ni) {
                int r = row0 + (w >> 1) * 64 + mi * 16 + g * 4;
                int c = col0 + (w & 1) * 64 + ni * 16 + c15;
                #pragma unroll
                for (int q = 0; q < 4; ++q) {
                    float v = acc[mi][ni][q];
                    C[(r + q) * NDIM + c] = v;
                    if (stage == 0) {
                        unsigned short hb = f2bf(v);
                        AAh[z * NN + (r + q) * NDIM + c] = hb;
                        AAl[z * NN + (r + q) * NDIM + c] = f2bf(v - bf2f(hb));
                    }
                }
            }
    } else {
        unsigned short* Cm = MIXbf + (z - 8) * NN;
        #pragma unroll
        for (int mi = 0; mi < 4; ++mi)
            #pragma unroll
            for (int ni = 0; ni < 4; ++ni) {
                int r = row0 + (w >> 1) * 64 + mi * 16 + g * 4;
                int c = col0 + (w & 1) * 64 + ni * 16 + c15;
                #pragma unroll
                for (int q = 0; q < 4; ++q)
                    Cm[(r + q) * NDIM + c] = f2bf(acc[mi][ni][q]);
            }
    }
}

// ---------------- Combine: temp[o,b,n,m] + per-(o,b) max-abs ----------------
// 8 elems/thread, grid (128, 8). use_tmp: store bf16 pre-norm tmp, else fp32 out.
__global__ __launch_bounds__(256) void combine_kernel(
    const unsigned short* __restrict__ s_bf, const unsigned short* __restrict__ Ah,
    const float* __restrict__ AA, const float* __restrict__ AAA,
    const unsigned short* __restrict__ MIXbf,
    const float* __restrict__ alpha, const float* __restrict__ beta,
    const float* __restrict__ coeffs,
    float* __restrict__ out, unsigned short* __restrict__ tmp,
    unsigned int* __restrict__ smax, int use_tmp)
{
    const int b  = blockIdx.y;
    const int e0 = blockIdx.x * 2048 + threadIdx.x * 8;
    const int n  = e0 >> 9;
    const int m0 = e0 & 511;

    float ca[8], cb[8], cc[8];
    #pragma unroll
    for (int o = 0; o < 8; ++o) {
        float c1 = 0.f, c2 = 0.f, c3 = 0.f;
        #pragma unroll
        for (int i = 0; i < 4; ++i) {
            c1 += coeffs[o * 16 + 4 + i];
            c2 += coeffs[o * 16 + 8 + i];
            c3 += coeffs[o * 16 + 12 + i];
        }
        ca[o] = c1 - 3.f * c3; cb[o] = 2.f * c2; cc[o] = 4.f * c3;
    }

    float av[8], aav[8], aaav[8], sv[4][8], mv[4][8];
    {
        usv8 a8 = *(const usv8*)(Ah + b * NN + e0);
        #pragma unroll
        for (int j = 0; j < 8; ++j) av[j] = bf2f(a8[j]);
        const float4 q0 = *(const float4*)(AA + b * NN + e0);
        const float4 q1 = *(const float4*)(AA + b * NN + e0 + 4);
        aav[0]=q0.x; aav[1]=q0.y; aav[2]=q0.z; aav[3]=q0.w;
        aav[4]=q1.x; aav[5]=q1.y; aav[6]=q1.z; aav[7]=q1.w;
        const float4 r0 = *(const float4*)(AAA + b * NN + e0);
        const float4 r1 = *(const float4*)(AAA + b * NN + e0 + 4);
        aaav[0]=r0.x; aaav[1]=r0.y; aaav[2]=r0.z; aaav[3]=r0.w;
        aaav[4]=r1.x; aaav[5]=r1.y; aaav[6]=r1.z; aaav[7]=r1.w;
        #pragma unroll
        for (int i = 0; i < 4; ++i) {
            usv8 s8 = *(const usv8*)(s_bf + (i * 8 + b) * NN + e0);
            usv8 m8 = *(const usv8*)(MIXbf + (i * 8 + b) * NN + e0);
            #pragma unroll
            for (int j = 0; j < 8; ++j) { sv[i][j] = bf2f(s8[j]); mv[i][j] = bf2f(m8[j]); }
        }
    }

    float lmax[8];
    #pragma unroll
    for (int o = 0; o < 8; ++o) {
        float outv[8];
        float lm = 0.f;
        #pragma unroll
        for (int j = 0; j < 8; ++j) {
            float t = ca[o] * av[j] + cb[o] * aav[j] + cc[o] * aaav[j];
            #pragma unroll
            for (int i = 0; i < 4; ++i)
                t += alpha[o * 4 + i] * sv[i][j] + beta[o * 4 + i] * mv[i][j];
            t *= 0.25f;
            if (n == m0 + j) t = 0.f;
            outv[j] = t;
            lm = fmaxf(lm, fabsf(t));
        }
        lmax[o] = lm;
        if (use_tmp) {
            usv8 ov;
            #pragma unroll
            for (int j = 0; j < 8; ++j) ov[j] = f2bf(outv[j]);
            *(usv8*)(tmp + (o * 8 + b) * NN + e0) = ov;
        } else {
            *(float4*)(out + (o * 8 + b) * NN + e0) =
                make_float4(outv[0], outv[1], outv[2], outv[3]);
            *(float4*)(out + (o * 8 + b) * NN + e0 + 4) =
                make_float4(outv[4], outv[5], outv[6], outv[7]);
        }
    }

    #pragma unroll
    for (int o = 0; o < 8; ++o) {
        #pragma unroll
        for (int off = 32; off > 0; off >>= 1)
            lmax[o] = fmaxf(lmax[o], __shfl_xor(lmax[o], off, 64));
    }
    __shared__ float red[4][8];
    const int lane = threadIdx.x & 63, wv = threadIdx.x >> 6;
    if (lane == 0) {
        #pragma unroll
        for (int o = 0; o < 8; ++o) red[wv][o] = lmax[o];
    }
    __syncthreads();
    if (threadIdx.x < 8) {
        const int o = threadIdx.x;
        const float mfin = fmaxf(fmaxf(red[0][o], red[1][o]), fmaxf(red[2][o], red[3][o]));
        atomicMax(&smax[o * 8 + b], __float_as_uint(mfin));
    }
}

// ---------------- Normalize + relu -> fp32 out ----------------
// 8 elems/thread, grid (128, 64)
__global__ __launch_bounds__(256) void norm_kernel(
    float* __restrict__ out, const unsigned short* __restrict__ tmp,
    const unsigned int* __restrict__ smax, const float* __restrict__ tau,
    int use_tmp)
{
    const int ob = blockIdx.y;
    const float mx = __uint_as_float(smax[ob]);
    const float inv = (mx == 0.f) ? 1.f : (1.f / mx);
    const float t = tau[ob >> 3];
    const int e0 = blockIdx.x * 2048 + threadIdx.x * 8;
    float v[8];
    if (use_tmp) {
        usv8 tv = *(const usv8*)(tmp + ob * NN + e0);
        #pragma unroll
        for (int j = 0; j < 8; ++j) v[j] = bf2f(tv[j]);
    } else {
        float4 v0 = *(float4*)(out + ob * NN + e0);
        float4 v1 = *(float4*)(out + ob * NN + e0 + 4);
        v[0]=v0.x; v[1]=v0.y; v[2]=v0.z; v[3]=v0.w;
        v[4]=v1.x; v[5]=v1.y; v[6]=v1.z; v[7]=v1.w;
    }
    #pragma unroll
    for (int j = 0; j < 8; ++j) v[j] = fmaxf(fmaf(v[j], inv, -t), 0.f);
    *(float4*)(out + ob * NN + e0)     = make_float4(v[0], v[1], v[2], v[3]);
    *(float4*)(out + ob * NN + e0 + 4) = make_float4(v[4], v[5], v[6], v[7]);
}

extern "C" void kernel_launch(void* const* d_in, const int* in_sizes, int n_in,
                              void* d_out, int out_size, void* d_ws, size_t ws_size,
                              hipStream_t stream) {
    (void)in_sizes; (void)n_in; (void)out_size;
    const float* s_in   = (const float*)d_in[0];  // (4,8,512,512)
    const float* a_o    = (const float*)d_in[1];  // (8,512,512)
    const float* alpha  = (const float*)d_in[2];  // (8,4)
    const float* beta   = (const float*)d_in[3];  // (8,4)
    const float* coeffs = (const float*)d_in[4];  // (8,4,4)
    const float* tau    = (const float*)d_in[5];  // (8)
    float* out = (float*)d_out;                   // (8,8,512,512)

    // workspace layout
    float* AA  = (float*)d_ws;                       // 8NN f32
    float* AAA = AA + 8 * NN;                        // 8NN f32
    unsigned short* s_bf  = (unsigned short*)(AAA + 8 * NN);  // 32NN bf16
    unsigned short* Ah    = s_bf + 32 * NN;          // 8NN
    unsigned short* Al    = Ah + 8 * NN;             // 8NN
    unsigned short* AAh   = Al + 8 * NN;             // 8NN
    unsigned short* AAl   = AAh + 8 * NN;            // 8NN
    unsigned short* MIXbf = AAl + 8 * NN;            // 32NN
    unsigned int* SMAX = (unsigned int*)(MIXbf + 32 * NN);    // 64
    unsigned short* TMP = (unsigned short*)(SMAX + 64);       // 64NN (optional)

    const size_t need_tmp = (size_t)((char*)(TMP + 64 * NN) - (char*)d_ws);
    const int use_tmp = (ws_size >= need_tmp) ? 1 : 0;

    hipLaunchKernelGGL(preconv_kernel, dim3(256, 40), dim3(256), 0, stream,
                       s_in, a_o, s_bf, Ah, Al);
    hipLaunchKernelGGL(gemm_fused_kernel, dim3(4, 4, 8), dim3(256), 0, stream,
                       s_bf, Ah, Al, AAh, AAl, AA, AAA, MIXbf, 0);   // AA
    hipLaunchKernelGGL(gemm_fused_kernel, dim3(4, 4, 40), dim3(256), 0, stream,
                       s_bf, Ah, Al, AAh, AAl, AA, AAA, MIXbf, 1);   // AAA + MIX
    hipMemsetAsync(SMAX, 0, 64 * sizeof(unsigned int), stream);
    hipLaunchKernelGGL(combine_kernel, dim3(128, 8), dim3(256), 0, stream,
                       s_bf, Ah, AA, AAA, MIXbf, alpha, beta, coeffs,
                       out, TMP, SMAX, use_tmp);
    hipLaunchKernelGGL(norm_kernel, dim3(128, 64), dim3(256), 0, stream,
                       out, TMP, SMAX, tau, use_tmp);
}

// Round 8
// 225.874 us; speedup vs baseline: 2.0610x; 1.1240x over previous
//
#include <hip/hip_runtime.h>

#define NDIM 512
#define NN (512*512)

typedef float          fv4  __attribute__((ext_vector_type(4)));
typedef unsigned int   uv2  __attribute__((ext_vector_type(2)));
typedef unsigned int   uv4  __attribute__((ext_vector_type(4)));
typedef unsigned short usv4 __attribute__((ext_vector_type(4)));
typedef unsigned short usv8 __attribute__((ext_vector_type(8)));
typedef short          sv8  __attribute__((ext_vector_type(8)));

__device__ __forceinline__ unsigned short f2bf(float x){
    unsigned u = __builtin_bit_cast(unsigned, x);
    u += 0x7fffu + ((u >> 16) & 1u);          // round-to-nearest-even
    return (unsigned short)(u >> 16);
}
__device__ __forceinline__ float bf2f(unsigned short s){
    unsigned u = ((unsigned)s) << 16;
    return __builtin_bit_cast(float, u);
}

// D += A*B, bf16 16x16x32 (builtin; short8 = 8 bf16 per operand)
#define MFMA16(acc, va, vb) \
    acc = __builtin_amdgcn_mfma_f32_16x16x32_bf16( \
        __builtin_bit_cast(sv8, va), __builtin_bit_cast(sv8, vb), acc, 0, 0, 0)

// hardware transpose read: 16-lane cluster reads its contiguous 128B subtile
// (addr(l) = base + 8*l B); lane l receives elems (l&15) + j*16 + (l>>4)*64
#define TRREAD(dst, addr) \
    asm volatile("ds_read_b64_tr_b16 %0, %1" : "=v"(dst) : "v"(addr))

// ---------------- pre-convert: s_in -> bf16, a_o -> hi/lo bf16 --------------
__global__ __launch_bounds__(256) void preconv_kernel(
    const float* __restrict__ s_in, const float* __restrict__ a_o,
    unsigned short* __restrict__ s_bf, unsigned short* __restrict__ Ah,
    unsigned short* __restrict__ Al)
{
    const int z  = blockIdx.y;
    const int e0 = blockIdx.x * 1024 + threadIdx.x * 4;
    if (z < 32) {
        float4 v = *(const float4*)(s_in + z * NN + e0);
        float vv[4] = {v.x, v.y, v.z, v.w};
        usv4 o;
        #pragma unroll
        for (int j = 0; j < 4; ++j) o[j] = f2bf(vv[j]);
        *(usv4*)(s_bf + z * NN + e0) = o;
    } else {
        const int b = z - 32;
        float4 v = *(const float4*)(a_o + b * NN + e0);
        float vv[4] = {v.x, v.y, v.z, v.w};
        usv4 h, l;
        #pragma unroll
        for (int j = 0; j < 4; ++j) {
            unsigned short hb = f2bf(vv[j]);
            h[j] = hb;
            l[j] = f2bf(vv[j] - bf2f(hb));
        }
        *(usv4*)(Ah + b * NN + e0) = h;
        *(usv4*)(Al + b * NN + e0) = l;
    }
}

// ---- unified GEMM kernel: double-buffered LDS, T14 split staging -----------
// stage==0: grid (4,4,8)  all blocks SPLIT: AA = A@A (fp32 + hi/lo bf16 out)
// stage==1: grid (4,4,40) z<8 SPLIT: AAA = A@AA (fp32)
//                         z>=8 MIX : MIXbf[z-8] = bf16(S@A + A@S)
__global__ __launch_bounds__(256) void gemm_fused_kernel(
    const unsigned short* __restrict__ s_bf,
    const unsigned short* __restrict__ Ah, const unsigned short* __restrict__ Al,
    unsigned short* __restrict__ AAh, unsigned short* __restrict__ AAl,
    float* __restrict__ AA, float* __restrict__ AAA,
    unsigned short* __restrict__ MIXbf, int stage)
{
    const int z = blockIdx.z;
    const bool split = (stage == 0) || (z < 8);

    const unsigned short *X1, *X2, *Y1, *Y2;
    if (stage == 0)      { X1 = Ah + z * NN;  X2 = Al + z * NN;
                           Y1 = Ah + z * NN;  Y2 = Al + z * NN; }
    else if (z < 8)      { X1 = Ah + z * NN;  X2 = Al + z * NN;
                           Y1 = AAh + z * NN; Y2 = AAl + z * NN; }
    else                 { const int z2 = z - 8, b = z2 & 7;
                           X1 = s_bf + z2 * NN; X2 = Ah + b * NN;
                           Y1 = Ah + b * NN;    Y2 = s_bf + z2 * NN; }

    const int row0 = blockIdx.y * 128, col0 = blockIdx.x * 128;
    const int tid = threadIdx.x, lane = tid & 63, w = tid >> 6;

    __shared__ unsigned short Xa[2][128][40], Xb[2][128][40];
    __shared__ unsigned short Ba[2][4096], Bb[2][4096];

    fv4 acc[4][4];
    #pragma unroll
    for (int mi = 0; mi < 4; ++mi)
        #pragma unroll
        for (int ni = 0; ni < 4; ++ni) acc[mi][ni] = (fv4)0.f;

    // ---- per-thread staging geometry (identical mappings to round 7) ----
    // X: chunk a -> row tid>>2, chunk b -> row 64+(tid>>2); col8 = (tid&3)*8
    const int xr  = tid >> 2, xc = (tid & 3) << 3;
    const int xo0 = (row0 + xr) * NDIM + xc;
    const int xo1 = xo0 + 64 * NDIM;
    // B: conflict-free subtiled [cs(8)][k(32)][c(16)]
    const int kl = tid & 3, hh = (tid >> 2) & 1, cs = (tid >> 3) & 7, kh = tid >> 6;
    const int kb0 = kh * 4 + kl;              // chunk a k; chunk b k = kb0+16
    const int yo0 = kb0 * NDIM + col0 + cs * 16 + hh * 8;
    const int yo1 = yo0 + 16 * NDIM;
    const int lb0 = cs * 512 + kb0 * 16 + hh * 8;
    const int lb1 = lb0 + 256;

    const unsigned laneoff = (((unsigned)lane >> 4) << 7) | (((unsigned)lane & 15) << 3);
    const unsigned wcol    = ((unsigned)(w & 1)) << 12;   // (w&1)*4 cs-blocks * 1024B
    const int g4 = (lane >> 4) * 4;

    usv8 lx1a, lx1b, lx2a, lx2b, ly1a, ly1b, ly2a, ly2b;

    auto gload = [&](int k0) {
        lx1a = *(const usv8*)(X1 + xo0 + k0);
        lx1b = *(const usv8*)(X1 + xo1 + k0);
        lx2a = *(const usv8*)(X2 + xo0 + k0);
        lx2b = *(const usv8*)(X2 + xo1 + k0);
        ly1a = *(const usv8*)(Y1 + yo0 + k0 * NDIM);
        ly1b = *(const usv8*)(Y1 + yo1 + k0 * NDIM);
        ly2a = *(const usv8*)(Y2 + yo0 + k0 * NDIM);
        ly2b = *(const usv8*)(Y2 + yo1 + k0 * NDIM);
    };
    auto swrite = [&](int buf) {
        *(usv8*)&Xa[buf][xr][xc]      = lx1a;
        *(usv8*)&Xa[buf][64 + xr][xc] = lx1b;
        *(usv8*)&Xb[buf][xr][xc]      = lx2a;
        *(usv8*)&Xb[buf][64 + xr][xc] = lx2b;
        *(usv8*)&Ba[buf][lb0] = ly1a;
        *(usv8*)&Ba[buf][lb1] = ly1b;
        *(usv8*)&Bb[buf][lb0] = ly2a;
        *(usv8*)&Bb[buf][lb1] = ly2b;
    };
    auto compute = [&](int buf) {
        const unsigned ba_base = (unsigned)(uintptr_t)&Ba[buf][0];
        const unsigned bb_base = (unsigned)(uintptr_t)&Bb[buf][0];
        uv2 fa[4][2], fb[4][2];
        #pragma unroll
        for (int ni = 0; ni < 4; ++ni)
            #pragma unroll
            for (int h = 0; h < 2; ++h) {
                TRREAD(fa[ni][h], ba_base + wcol + laneoff + ni * 1024 + h * 512);
                TRREAD(fb[ni][h], bb_base + wcol + laneoff + ni * 1024 + h * 512);
            }
        asm volatile("s_waitcnt lgkmcnt(0)" ::: "memory");
        __builtin_amdgcn_sched_barrier(0);

        #pragma unroll
        for (int mi = 0; mi < 4; ++mi) {
            const unsigned short* xr1 = &Xa[buf][(w >> 1) * 64 + mi * 16 + (lane & 15)][0];
            const unsigned short* xr2 = &Xb[buf][(w >> 1) * 64 + mi * 16 + (lane & 15)][0];
            uv2 a0 = *(const uv2*)(xr1 + g4);
            uv2 a1 = *(const uv2*)(xr1 + 16 + g4);
            uv2 b0 = *(const uv2*)(xr2 + g4);
            uv2 b1 = *(const uv2*)(xr2 + 16 + g4);
            uv4 xva = {a0.x, a0.y, a1.x, a1.y};
            uv4 xvb = {b0.x, b0.y, b1.x, b1.y};
            #pragma unroll
            for (int ni = 0; ni < 4; ++ni) {
                uv4 vba = {fa[ni][0].x, fa[ni][0].y, fa[ni][1].x, fa[ni][1].y};
                uv4 vbb = {fb[ni][0].x, fb[ni][0].y, fb[ni][1].x, fb[ni][1].y};
                if (split) {
                    MFMA16(acc[mi][ni], xva, vba);   // hi*hi
                    MFMA16(acc[mi][ni], xva, vbb);   // hi*lo
                    MFMA16(acc[mi][ni], xvb, vba);   // lo*hi
                } else {
                    MFMA16(acc[mi][ni], xva, vba);   // S@A
                    MFMA16(acc[mi][ni], xvb, vbb);   // A@S
                }
            }
        }
    };

    // ---- 2-phase pipeline: one barrier per K-step ----
    gload(0);
    swrite(0);
    __syncthreads();
    int cur = 0;
    for (int t = 0; t < 15; ++t) {
        gload((t + 1) * 32);     // issue early (T14): latency hides under compute
        compute(cur);
        swrite(cur ^ 1);         // vmcnt drain happens here, after compute
        __syncthreads();         // single barrier: writers touched the idle buffer
        cur ^= 1;
    }
    compute(cur);

    const int g = lane >> 4, c15 = lane & 15;
    if (split) {
        float* C = (stage == 0) ? (AA + z * NN) : (AAA + z * NN);
        #pragma unroll
        for (int mi = 0; mi < 4; ++mi)
            #pragma unroll
            for (int ni = 0; ni < 4; ++ni) {
                int r = row0 + (w >> 1) * 64 + mi * 16 + g * 4;
                int c = col0 + (w & 1) * 64 + ni * 16 + c15;
                #pragma unroll
                for (int q = 0; q < 4; ++q) {
                    float v = acc[mi][ni][q];
                    C[(r + q) * NDIM + c] = v;
                    if (stage == 0) {
                        unsigned short hb = f2bf(v);
                        AAh[z * NN + (r + q) * NDIM + c] = hb;
                        AAl[z * NN + (r + q) * NDIM + c] = f2bf(v - bf2f(hb));
                    }
                }
            }
    } else {
        unsigned short* Cm = MIXbf + (z - 8) * NN;
        #pragma unroll
        for (int mi = 0; mi < 4; ++mi)
            #pragma unroll
            for (int ni = 0; ni < 4; ++ni) {
                int r = row0 + (w >> 1) * 64 + mi * 16 + g * 4;
                int c = col0 + (w & 1) * 64 + ni * 16 + c15;
                #pragma unroll
                for (int q = 0; q < 4; ++q)
                    Cm[(r + q) * NDIM + c] = f2bf(acc[mi][ni][q]);
            }
    }
}

// ---------------- Combine: temp[o,b,n,m] + per-(o,b) max-abs ----------------
// 8 elems/thread, grid (128, 8). use_tmp: store bf16 pre-norm tmp, else fp32 out.
__global__ __launch_bounds__(256) void combine_kernel(
    const unsigned short* __restrict__ s_bf, const unsigned short* __restrict__ Ah,
    const float* __restrict__ AA, const float* __restrict__ AAA,
    const unsigned short* __restrict__ MIXbf,
    const float* __restrict__ alpha, const float* __restrict__ beta,
    const float* __restrict__ coeffs,
    float* __restrict__ out, unsigned short* __restrict__ tmp,
    unsigned int* __restrict__ smax, int use_tmp)
{
    const int b  = blockIdx.y;
    const int e0 = blockIdx.x * 2048 + threadIdx.x * 8;
    const int n  = e0 >> 9;
    const int m0 = e0 & 511;

    float ca[8], cb[8], cc[8];
    #pragma unroll
    for (int o = 0; o < 8; ++o) {
        float c1 = 0.f, c2 = 0.f, c3 = 0.f;
        #pragma unroll
        for (int i = 0; i < 4; ++i) {
            c1 += coeffs[o * 16 + 4 + i];
            c2 += coeffs[o * 16 + 8 + i];
            c3 += coeffs[o * 16 + 12 + i];
        }
        ca[o] = c1 - 3.f * c3; cb[o] = 2.f * c2; cc[o] = 4.f * c3;
    }

    float av[8], aav[8], aaav[8], sv[4][8], mv[4][8];
    {
        usv8 a8 = *(const usv8*)(Ah + b * NN + e0);
        #pragma unroll
        for (int j = 0; j < 8; ++j) av[j] = bf2f(a8[j]);
        const float4 q0 = *(const float4*)(AA + b * NN + e0);
        const float4 q1 = *(const float4*)(AA + b * NN + e0 + 4);
        aav[0]=q0.x; aav[1]=q0.y; aav[2]=q0.z; aav[3]=q0.w;
        aav[4]=q1.x; aav[5]=q1.y; aav[6]=q1.z; aav[7]=q1.w;
        const float4 r0 = *(const float4*)(AAA + b * NN + e0);
        const float4 r1 = *(const float4*)(AAA + b * NN + e0 + 4);
        aaav[0]=r0.x; aaav[1]=r0.y; aaav[2]=r0.z; aaav[3]=r0.w;
        aaav[4]=r1.x; aaav[5]=r1.y; aaav[6]=r1.z; aaav[7]=r1.w;
        #pragma unroll
        for (int i = 0; i < 4; ++i) {
            usv8 s8 = *(const usv8*)(s_bf + (i * 8 + b) * NN + e0);
            usv8 m8 = *(const usv8*)(MIXbf + (i * 8 + b) * NN + e0);
            #pragma unroll
            for (int j = 0; j < 8; ++j) { sv[i][j] = bf2f(s8[j]); mv[i][j] = bf2f(m8[j]); }
        }
    }

    float lmax[8];
    #pragma unroll
    for (int o = 0; o < 8; ++o) {
        float outv[8];
        float lm = 0.f;
        #pragma unroll
        for (int j = 0; j < 8; ++j) {
            float t = ca[o] * av[j] + cb[o] * aav[j] + cc[o] * aaav[j];
            #pragma unroll
            for (int i = 0; i < 4; ++i)
                t += alpha[o * 4 + i] * sv[i][j] + beta[o * 4 + i] * mv[i][j];
            t *= 0.25f;
            if (n == m0 + j) t = 0.f;
            outv[j] = t;
            lm = fmaxf(lm, fabsf(t));
        }
        lmax[o] = lm;
        if (use_tmp) {
            usv8 ov;
            #pragma unroll
            for (int j = 0; j < 8; ++j) ov[j] = f2bf(outv[j]);
            *(usv8*)(tmp + (o * 8 + b) * NN + e0) = ov;
        } else {
            *(float4*)(out + (o * 8 + b) * NN + e0) =
                make_float4(outv[0], outv[1], outv[2], outv[3]);
            *(float4*)(out + (o * 8 + b) * NN + e0 + 4) =
                make_float4(outv[4], outv[5], outv[6], outv[7]);
        }
    }

    #pragma unroll
    for (int o = 0; o < 8; ++o) {
        #pragma unroll
        for (int off = 32; off > 0; off >>= 1)
            lmax[o] = fmaxf(lmax[o], __shfl_xor(lmax[o], off, 64));
    }
    __shared__ float red[4][8];
    const int lane = threadIdx.x & 63, wv = threadIdx.x >> 6;
    if (lane == 0) {
        #pragma unroll
        for (int o = 0; o < 8; ++o) red[wv][o] = lmax[o];
    }
    __syncthreads();
    if (threadIdx.x < 8) {
        const int o = threadIdx.x;
        const float mfin = fmaxf(fmaxf(red[0][o], red[1][o]), fmaxf(red[2][o], red[3][o]));
        atomicMax(&smax[o * 8 + b], __float_as_uint(mfin));
    }
}

// ---------------- Normalize + relu -> fp32 out ----------------
// 8 elems/thread, grid (128, 64)
__global__ __launch_bounds__(256) void norm_kernel(
    float* __restrict__ out, const unsigned short* __restrict__ tmp,
    const unsigned int* __restrict__ smax, const float* __restrict__ tau,
    int use_tmp)
{
    const int ob = blockIdx.y;
    const float mx = __uint_as_float(smax[ob]);
    const float inv = (mx == 0.f) ? 1.f : (1.f / mx);
    const float t = tau[ob >> 3];
    const int e0 = blockIdx.x * 2048 + threadIdx.x * 8;
    float v[8];
    if (use_tmp) {
        usv8 tv = *(const usv8*)(tmp + ob * NN + e0);
        #pragma unroll
        for (int j = 0; j < 8; ++j) v[j] = bf2f(tv[j]);
    } else {
        float4 v0 = *(float4*)(out + ob * NN + e0);
        float4 v1 = *(float4*)(out + ob * NN + e0 + 4);
        v[0]=v0.x; v[1]=v0.y; v[2]=v0.z; v[3]=v0.w;
        v[4]=v1.x; v[5]=v1.y; v[6]=v1.z; v[7]=v1.w;
    }
    #pragma unroll
    for (int j = 0; j < 8; ++j) v[j] = fmaxf(fmaf(v[j], inv, -t), 0.f);
    *(float4*)(out + ob * NN + e0)     = make_float4(v[0], v[1], v[2], v[3]);
    *(float4*)(out + ob * NN + e0 + 4) = make_float4(v[4], v[5], v[6], v[7]);
}

extern "C" void kernel_launch(void* const* d_in, const int* in_sizes, int n_in,
                              void* d_out, int out_size, void* d_ws, size_t ws_size,
                              hipStream_t stream) {
    (void)in_sizes; (void)n_in; (void)out_size;
    const float* s_in   = (const float*)d_in[0];  // (4,8,512,512)
    const float* a_o    = (const float*)d_in[1];  // (8,512,512)
    const float* alpha  = (const float*)d_in[2];  // (8,4)
    const float* beta   = (const float*)d_in[3];  // (8,4)
    const float* coeffs = (const float*)d_in[4];  // (8,4,4)
    const float* tau    = (const float*)d_in[5];  // (8)
    float* out = (float*)d_out;                   // (8,8,512,512)

    // workspace layout
    float* AA  = (float*)d_ws;                       // 8NN f32
    float* AAA = AA + 8 * NN;                        // 8NN f32
    unsigned short* s_bf  = (unsigned short*)(AAA + 8 * NN);  // 32NN bf16
    unsigned short* Ah    = s_bf + 32 * NN;          // 8NN
    unsigned short* Al    = Ah + 8 * NN;             // 8NN
    unsigned short* AAh   = Al + 8 * NN;             // 8NN
    unsigned short* AAl   = AAh + 8 * NN;            // 8NN
    unsigned short* MIXbf = AAl + 8 * NN;            // 32NN
    unsigned int* SMAX = (unsigned int*)(MIXbf + 32 * NN);    // 64
    unsigned short* TMP = (unsigned short*)(SMAX + 64);       // 64NN (optional)

    const size_t need_tmp = (size_t)((char*)(TMP + 64 * NN) - (char*)d_ws);
    const int use_tmp = (ws_size >= need_tmp) ? 1 : 0;

    hipLaunchKernelGGL(preconv_kernel, dim3(256, 40), dim3(256), 0, stream,
                       s_in, a_o, s_bf, Ah, Al);
    hipLaunchKernelGGL(gemm_fused_kernel, dim3(4, 4, 8), dim3(256), 0, stream,
                       s_bf, Ah, Al, AAh, AAl, AA, AAA, MIXbf, 0);   // AA
    hipLaunchKernelGGL(gemm_fused_kernel, dim3(4, 4, 40), dim3(256), 0, stream,
                       s_bf, Ah, Al, AAh, AAl, AA, AAA, MIXbf, 1);   // AAA + MIX
    hipMemsetAsync(SMAX, 0, 64 * sizeof(unsigned int), stream);
    hipLaunchKernelGGL(combine_kernel, dim3(128, 8), dim3(256), 0, stream,
                       s_bf, Ah, AA, AAA, MIXbf, alpha, beta, coeffs,
                       out, TMP, SMAX, use_tmp);
    hipLaunchKernelGGL(norm_kernel, dim3(128, 64), dim3(256), 0, stream,
                       out, TMP, SMAX, tau, use_tmp);
}